// Round 10
// baseline (247.632 us; speedup 1.0000x reference)
//
#include <hip/hip_runtime.h>

// Pipeline: cvt(x,Wqkv,Wproj) -> GEMM qkv + fused bias/l2norm/scale/split (Q pre-scaled
//           smh*log2e) -> bias_prep (bias*log2e) -> v_transpose ->
//           flash attn (QBLK=64, swapped-QK^T, bias-in-acc, in-register P,
//                       2-deep reg-staged dbuf K/V, 1 barrier/iter) -> GEMM proj(f32+bias)
// B=2 L=2048 C=1024 H=16 D=64. All matmuls bf16 MFMA 16x16x32, f32 accumulate.

typedef __bf16 bf16x8 __attribute__((ext_vector_type(8)));
typedef __bf16 bf16x4 __attribute__((ext_vector_type(4)));
typedef float  f32x4  __attribute__((ext_vector_type(4)));

#define BB 2
#define LL 2048
#define CC 1024
#define HH 16
#define DD 64
#define LOG2E 1.44269504088896f

__device__ __forceinline__ f32x4 mfma_16x16x32(bf16x8 a, bf16x8 b, f32x4 c) {
    return __builtin_amdgcn_mfma_f32_16x16x32_bf16(a, b, c, 0, 0, 0);
}

// async global->LDS, 16B per lane; LDS dest = wave-uniform base + lane*16
__device__ __forceinline__ void gload_lds16(const __bf16* g, __bf16* lds) {
    __builtin_amdgcn_global_load_lds(
        (const __attribute__((address_space(1))) unsigned int*)g,
        (__attribute__((address_space(3))) unsigned int*)lds,
        16, 0, 0);
}

__device__ __forceinline__ unsigned pk_bf16(float a, float b) {
    unsigned short ua = __builtin_bit_cast(unsigned short, (__bf16)a);
    unsigned short ub = __builtin_bit_cast(unsigned short, (__bf16)b);
    return (unsigned)ua | ((unsigned)ub << 16);
}

// ---------------- f32 -> bf16 convert ----------------
__global__ __launch_bounds__(256) void cvt_bf16_kernel(const float* __restrict__ in,
                                                       __bf16* __restrict__ out, int n4) {
    int i = blockIdx.x * 256 + threadIdx.x;
    if (i >= n4) return;
    float4 v = reinterpret_cast<const float4*>(in)[i];
    bf16x4 o;
    o[0] = (__bf16)v.x; o[1] = (__bf16)v.y; o[2] = (__bf16)v.z; o[3] = (__bf16)v.w;
    reinterpret_cast<bf16x4*>(out)[i] = o;
}

// ---------------- bias prep: rowmax + bf16((bias - rowmax)*log2e) ----------------
__global__ __launch_bounds__(256) void bias_prep_kernel(const float* __restrict__ bias,
                                                        __bf16* __restrict__ bias_bf) {
    __shared__ float wmax[4];
    const int l = blockIdx.x, tid = threadIdx.x;
    const int w = tid >> 6;
    float4 a = reinterpret_cast<const float4*>(bias + (size_t)l * 2048)[tid];
    float4 b = reinterpret_cast<const float4*>(bias + (size_t)l * 2048 + 1024)[tid];
    float m = fmaxf(fmaxf(fmaxf(a.x, a.y), fmaxf(a.z, a.w)),
                    fmaxf(fmaxf(b.x, b.y), fmaxf(b.z, b.w)));
#pragma unroll
    for (int off = 1; off < 64; off <<= 1) m = fmaxf(m, __shfl_xor(m, off, 64));
    if ((tid & 63) == 0) wmax[w] = m;
    __syncthreads();
    float M = fmaxf(fmaxf(wmax[0], wmax[1]), fmaxf(wmax[2], wmax[3]));
    bf16x4 o0, o1;
    o0[0] = (__bf16)((a.x - M) * LOG2E); o0[1] = (__bf16)((a.y - M) * LOG2E);
    o0[2] = (__bf16)((a.z - M) * LOG2E); o0[3] = (__bf16)((a.w - M) * LOG2E);
    o1[0] = (__bf16)((b.x - M) * LOG2E); o1[1] = (__bf16)((b.y - M) * LOG2E);
    o1[2] = (__bf16)((b.z - M) * LOG2E); o1[3] = (__bf16)((b.w - M) * LOG2E);
    reinterpret_cast<bf16x4*>(bias_bf + (size_t)l * 2048)[tid] = o0;
    reinterpret_cast<bf16x4*>(bias_bf + (size_t)l * 2048 + 1024)[tid] = o1;
}

// ---------------- QKV GEMM + fused bias/l2norm/scale/split ----------------
__global__ __launch_bounds__(256) void gemm_qkv_fused_kernel(
    const __bf16* __restrict__ A, const __bf16* __restrict__ Bm,
    const float* __restrict__ q_bias, const float* __restrict__ v_bias,
    const float* __restrict__ scale_mul,
    __bf16* __restrict__ Qw, __bf16* __restrict__ Kw, __bf16* __restrict__ Vw) {
    __shared__ __bf16 As[128 * 64];   // LDS[row][c] = A[row][c ^ ((row&7)<<4)]  (byte view)
    __shared__ __bf16 Bs[128 * 64];
    const int tid = threadIdx.x;
    const int K = 1024;
    const int nwg = gridDim.x * gridDim.y;
    const int flat = blockIdx.y * gridDim.x + blockIdx.x;
    const int wg = (flat & 7) * (nwg >> 3) + (flat >> 3);
    const int m0 = (wg % gridDim.x) * 128, n0 = (wg / gridDim.x) * 128;
    const int w  = tid >> 6, l = tid & 63;
    const int wr = (w >> 1) * 64, wc = (w & 1) * 64;
    const int lr = l & 15, lg = l >> 4;
    const int rmask = (lr & 7) << 4;
    f32x4 acc[4][4] = {};
    const int lrow = l >> 3;
    const int celem = (((l & 7) ^ lrow) << 3);

    for (int kt = 0; kt < K; kt += 64) {
        __syncthreads();
#pragma unroll
        for (int i = 0; i < 4; ++i) {
            const int row = w * 32 + i * 8;
            gload_lds16(A + (size_t)(m0 + row + lrow) * K + kt + celem, &As[row * 64]);
            gload_lds16(Bm + (size_t)(n0 + row + lrow) * K + kt + celem, &Bs[row * 64]);
        }
        asm volatile("s_waitcnt vmcnt(0)" ::: "memory");
        __syncthreads();
#pragma unroll
        for (int kk = 0; kk < 2; ++kk) {
            bf16x8 af[4], bfr[4];
#pragma unroll
            for (int m = 0; m < 4; ++m)
                af[m] = *reinterpret_cast<const bf16x8*>(
                    (char*)As + (wr + m * 16 + lr) * 128 + ((kk * 64 + lg * 16) ^ rmask));
#pragma unroll
            for (int n = 0; n < 4; ++n)
                bfr[n] = *reinterpret_cast<const bf16x8*>(
                    (char*)Bs + (wc + n * 16 + lr) * 128 + ((kk * 64 + lg * 16) ^ rmask));
#pragma unroll
            for (int m = 0; m < 4; ++m)
#pragma unroll
                for (int n = 0; n < 4; ++n)
                    acc[m][n] = mfma_16x16x32(af[m], bfr[n], acc[m][n]);
        }
    }

    // ---- fused epilogue ----
    const int gcbase = n0 + wc;
    const int type = gcbase >> 10;           // 0=q, 1=k, 2=v
    const int h = (gcbase & 1023) >> 6;
    float qscale = 1.0f;
    if (type == 0) qscale = __expf(fminf(scale_mul[h], 4.60517019f)) * LOG2E;
    __bf16* dst = (type == 0) ? Qw : (type == 1) ? Kw : Vw;

#pragma unroll
    for (int m = 0; m < 4; ++m) {
        if (type != 1) {
            const float* bptr = (type == 0) ? q_bias : v_bias;
#pragma unroll
            for (int n = 0; n < 4; ++n) {
                float bv = bptr[(gcbase & 1023) + n * 16 + lr];
#pragma unroll
                for (int r = 0; r < 4; ++r) acc[m][n][r] += bv;
            }
        }
        float rs[4];
        if (type < 2) {
#pragma unroll
            for (int r = 0; r < 4; ++r) {
                float ss = 0.f;
#pragma unroll
                for (int n = 0; n < 4; ++n) ss += acc[m][n][r] * acc[m][n][r];
                rs[r] = ss;
            }
#pragma unroll
            for (int off = 1; off < 16; off <<= 1)
#pragma unroll
                for (int r = 0; r < 4; ++r) rs[r] += __shfl_xor(rs[r], off, 64);
#pragma unroll
            for (int r = 0; r < 4; ++r)
                rs[r] = ((type == 0) ? qscale : 1.0f) / fmaxf(sqrtf(rs[r]), 1e-12f);
        } else {
#pragma unroll
            for (int r = 0; r < 4; ++r) rs[r] = 1.0f;
        }
        const int rowg = m0 + wr + m * 16 + lg * 4;
#pragma unroll
        for (int n = 0; n < 4; ++n) {
            const int d = n * 16 + lr;
#pragma unroll
            for (int r = 0; r < 4; ++r) {
                const int row = rowg + r;
                const int bb = row >> 11, ll = row & 2047;
                dst[((size_t)((bb << 4) + h) * 2048 + ll) * 64 + d] =
                    (__bf16)(acc[m][n][r] * rs[r]);
            }
        }
    }
}

// ---------------- GEMM proj: C = A*B^T + bias (f32 out), m97 + XCD swz ----------
__global__ __launch_bounds__(256) void gemm_proj_kernel(
    const __bf16* __restrict__ A, const __bf16* __restrict__ Bm,
    float* __restrict__ Cf, const float* __restrict__ bias, int M, int N, int K) {
    __shared__ __bf16 As[128 * 64];
    __shared__ __bf16 Bs[128 * 64];
    const int tid = threadIdx.x;
    const int nwg = gridDim.x * gridDim.y;
    const int flat = blockIdx.y * gridDim.x + blockIdx.x;
    const int wg = (flat & 7) * (nwg >> 3) + (flat >> 3);
    const int m0 = (wg % gridDim.x) * 128, n0 = (wg / gridDim.x) * 128;
    const int w  = tid >> 6, l = tid & 63;
    const int wr = (w >> 1) * 64, wc = (w & 1) * 64;
    const int lr = l & 15, lg = l >> 4;
    const int rmask = (lr & 7) << 4;
    f32x4 acc[4][4] = {};
    const int lrow = l >> 3;
    const int celem = (((l & 7) ^ lrow) << 3);

    for (int kt = 0; kt < K; kt += 64) {
        __syncthreads();
#pragma unroll
        for (int i = 0; i < 4; ++i) {
            const int row = w * 32 + i * 8;
            gload_lds16(A + (size_t)(m0 + row + lrow) * K + kt + celem, &As[row * 64]);
            gload_lds16(Bm + (size_t)(n0 + row + lrow) * K + kt + celem, &Bs[row * 64]);
        }
        asm volatile("s_waitcnt vmcnt(0)" ::: "memory");
        __syncthreads();
#pragma unroll
        for (int kk = 0; kk < 2; ++kk) {
            bf16x8 af[4], bfr[4];
#pragma unroll
            for (int m = 0; m < 4; ++m)
                af[m] = *reinterpret_cast<const bf16x8*>(
                    (char*)As + (wr + m * 16 + lr) * 128 + ((kk * 64 + lg * 16) ^ rmask));
#pragma unroll
            for (int n = 0; n < 4; ++n)
                bfr[n] = *reinterpret_cast<const bf16x8*>(
                    (char*)Bs + (wc + n * 16 + lr) * 128 + ((kk * 64 + lg * 16) ^ rmask));
#pragma unroll
            for (int m = 0; m < 4; ++m)
#pragma unroll
                for (int n = 0; n < 4; ++n)
                    acc[m][n] = mfma_16x16x32(af[m], bfr[n], acc[m][n]);
        }
    }
#pragma unroll
    for (int m = 0; m < 4; ++m)
#pragma unroll
        for (int n = 0; n < 4; ++n) {
            const int row = m0 + wr + m * 16 + lg * 4;
            const int col = n0 + wc + n * 16 + lr;
#pragma unroll
            for (int r = 0; r < 4; ++r)
                Cf[(size_t)(row + r) * N + col] = acc[m][n][r] + bias[col];
        }
}

// ---------------- V transpose: (B,H,L,D) -> (B,H,D,L) ----------------
__global__ __launch_bounds__(256) void v_transpose_kernel(const __bf16* __restrict__ Vin,
                                                          __bf16* __restrict__ Vt) {
    __shared__ __bf16 T[64][72];
    const int lb = blockIdx.x, bh = blockIdx.y;
    const int tid = threadIdx.x;
    const size_t base = (size_t)bh * LL * DD;
    const int row = tid >> 2, c = (tid & 3) * 16;
    {
        const __bf16* src = Vin + base + (size_t)(lb * 64 + row) * 64 + c;
        *reinterpret_cast<bf16x8*>(&T[row][c])     = *reinterpret_cast<const bf16x8*>(src);
        *reinterpret_cast<bf16x8*>(&T[row][c + 8]) = *reinterpret_cast<const bf16x8*>(src + 8);
    }
    __syncthreads();
    bf16x8 o0, o1;
#pragma unroll
    for (int j = 0; j < 8; ++j) {
        o0[j] = T[c + j][row];
        o1[j] = T[c + 8 + j][row];
    }
    __bf16* dst = Vt + base + (size_t)row * 2048 + lb * 64 + c;
    *reinterpret_cast<bf16x8*>(dst)     = o0;
    *reinterpret_cast<bf16x8*>(dst + 8) = o1;
}

// ---------------- flash attention: R9 structure, 2-deep reg prefetch, no setprio ----------
// grid (bh=32, qb=32); 256 threads = 4 waves; wave w owns q-rows [qb*64+w*16, +16).
// Loads for tile kb+2 issue at iter kb; LDS write of tile kb+1 at end of iter kb uses regs
// loaded at iter kb-1 (~2 compute phases of latency cover; newer loads stay in flight).
__global__ __launch_bounds__(256, 4) void attn_kernel(
    const __bf16* __restrict__ Q, const __bf16* __restrict__ K,
    const __bf16* __restrict__ Vt, const __bf16* __restrict__ biasL,
    const float* __restrict__ scale_mul, __bf16* __restrict__ Octx) {
    __shared__ __bf16 KVs[2][2][64 * 64];   // [buf][K/V]; LDS[row][c]=G[row][c^((row&7)<<4)]
    const int bh = blockIdx.x, qb = blockIdx.y;
    const int tid = threadIdx.x;
    const int w = tid >> 6, l = tid & 63;
    const int lr = l & 15, lg = l >> 4;
    const int rmask = (lr & 7) << 4;
    const int b = bh >> 4, h = bh & 15;
    const size_t base = (size_t)bh * LL * DD;
    const float smh = __expf(fminf(scale_mul[h], 4.60517019f));
    const float cexp = -smh * LOG2E;

    const int gq = qb * 64 + w * 16 + lr;
    bf16x8 qf[2];
    qf[0] = *reinterpret_cast<const bf16x8*>(Q + base + (size_t)gq * 64 + lg * 8);
    qf[1] = *reinterpret_cast<const bf16x8*>(Q + base + (size_t)gq * 64 + 32 + lg * 8);
    const __bf16* brow = biasL + (size_t)gq * 2048 + lg * 4;

    const int srow = tid >> 2;
    const int scb  = (tid & 3) * 32;
    const int smask = (srow & 7) << 4;
    const __bf16* kgbase = K  + base + (size_t)srow * 64   + (tid & 3) * 16;
    const __bf16* vgbase = Vt + base + (size_t)srow * 2048 + (tid & 3) * 16;

    // two staging register sets (static, no runtime indexing)
    bf16x8 kA0, kA1, vA0, vA1, kB0, kB1, vB0, vB1;
#define STAGE_LOAD(S, kb_)                                                        \
    {                                                                             \
        const __bf16* kg = kgbase + (size_t)(kb_) * 64 * 64;                      \
        k##S##0 = *reinterpret_cast<const bf16x8*>(kg);                           \
        k##S##1 = *reinterpret_cast<const bf16x8*>(kg + 8);                       \
        const __bf16* vg = vgbase + (kb_) * 64;                                   \
        v##S##0 = *reinterpret_cast<const bf16x8*>(vg);                           \
        v##S##1 = *reinterpret_cast<const bf16x8*>(vg + 8);                       \
    }
#define STAGE_WRITE(S, buf)                                                       \
    {                                                                             \
        char* kp = (char*)KVs[buf][0] + srow * 128;                               \
        char* vp = (char*)KVs[buf][1] + srow * 128;                               \
        *reinterpret_cast<bf16x8*>(kp + (scb ^ smask))        = k##S##0;          \
        *reinterpret_cast<bf16x8*>(kp + ((scb + 16) ^ smask)) = k##S##1;          \
        *reinterpret_cast<bf16x8*>(vp + (scb ^ smask))        = v##S##0;          \
        *reinterpret_cast<bf16x8*>(vp + ((scb + 16) ^ smask)) = v##S##1;          \
    }

    f32x4 Oa[4] = {};
    float lsum = 0.f;
    bf16x4 bcur[4];
#pragma unroll
    for (int t = 0; t < 4; ++t)
        bcur[t] = *reinterpret_cast<const bf16x4*>(brow + t * 16);

    // prologue: tile 0 -> LDS buf0; tile 1 loads in flight in set B
    STAGE_LOAD(A, 0);
    STAGE_WRITE(A, 0);
    STAGE_LOAD(B, 1);

    auto compute = [&](const char* Kc, const char* Vc, bf16x4 (&bv)[4]) {
        // acc init = bias*log2e + cexp
        f32x4 sa[4];
#pragma unroll
        for (int t = 0; t < 4; ++t)
#pragma unroll
            for (int r = 0; r < 4; ++r)
                sa[t][r] = (float)bv[t][r] + cexp;
        // S^T·log2e : lane holds q=lr, k = 16t+4lg+r
#pragma unroll
        for (int t = 0; t < 4; ++t) {
            const char* kr = Kc + (t * 16 + lr) * 128;
            bf16x8 kf0 = *reinterpret_cast<const bf16x8*>(kr + ((lg * 16) ^ rmask));
            bf16x8 kf1 = *reinterpret_cast<const bf16x8*>(kr + ((64 + lg * 16) ^ rmask));
            sa[t] = mfma_16x16x32(kf0, qf[0], sa[t]);
            sa[t] = mfma_16x16x32(kf1, qf[1], sa[t]);
        }
        // softmax: p = exp2(sa), lane-local pack into A-operand slots
        float p[4][4];
#pragma unroll
        for (int t = 0; t < 4; ++t)
#pragma unroll
            for (int r = 0; r < 4; ++r) {
                p[t][r] = exp2f(sa[t][r]);
                lsum += p[t][r];
            }
        union Upa { unsigned u[4]; bf16x8 v; } pa0, pa1;
        pa0.u[0] = pk_bf16(p[0][0], p[0][1]); pa0.u[1] = pk_bf16(p[0][2], p[0][3]);
        pa0.u[2] = pk_bf16(p[1][0], p[1][1]); pa0.u[3] = pk_bf16(p[1][2], p[1][3]);
        pa1.u[0] = pk_bf16(p[2][0], p[2][1]); pa1.u[1] = pk_bf16(p[2][2], p[2][3]);
        pa1.u[2] = pk_bf16(p[3][0], p[3][1]); pa1.u[3] = pk_bf16(p[3][2], p[3][3]);
        // O += P·V, permuted k-rows folded into vf addressing (b64 reads)
#pragma unroll
        for (int t = 0; t < 4; ++t) {
            const char* vr = Vc + (t * 16 + lr) * 128;
            union Uv { uint2 d[2]; bf16x8 v; } vf0, vf1;
            vf0.d[0] = *reinterpret_cast<const uint2*>(vr + ((lg * 8) ^ rmask));
            vf0.d[1] = *reinterpret_cast<const uint2*>(vr + ((32 + lg * 8) ^ rmask));
            vf1.d[0] = *reinterpret_cast<const uint2*>(vr + ((64 + lg * 8) ^ rmask));
            vf1.d[1] = *reinterpret_cast<const uint2*>(vr + ((96 + lg * 8) ^ rmask));
            Oa[t] = mfma_16x16x32(pa0.v, vf0.v, Oa[t]);
            Oa[t] = mfma_16x16x32(pa1.v, vf1.v, Oa[t]);
        }
    };

    auto load_bias = [&](int kb, bf16x4 (&bv)[4]) {
#pragma unroll
        for (int t = 0; t < 4; ++t)
            bv[t] = *reinterpret_cast<const bf16x4*>(brow + kb * 64 + t * 16);
    };

#pragma unroll 1
    for (int kb = 0; kb < 32; kb += 2) {
        // ---- even sub-iter: compute buf0 (tile kb) ----
        __syncthreads();
        if (kb + 2 < 32) STAGE_LOAD(A, kb + 2);       // 2-deep issue
        bf16x4 bnext[4];
        load_bias(kb + 1, bnext);
        compute((const char*)KVs[0][0], (const char*)KVs[0][1], bcur);
        STAGE_WRITE(B, 1);                            // tile kb+1, loaded one iter ago
#pragma unroll
        for (int t = 0; t < 4; ++t) bcur[t] = bnext[t];

        // ---- odd sub-iter: compute buf1 (tile kb+1) ----
        __syncthreads();
        if (kb + 3 < 32) STAGE_LOAD(B, kb + 3);
        if (kb + 2 < 32) load_bias(kb + 2, bnext);
        compute((const char*)KVs[1][0], (const char*)KVs[1][1], bcur);
        if (kb + 2 < 32) {
            STAGE_WRITE(A, 0);                        // tile kb+2
#pragma unroll
            for (int t = 0; t < 4; ++t) bcur[t] = bnext[t];
        }
    }
#undef STAGE_LOAD
#undef STAGE_WRITE

    // reduce lsum: partials for q=lr live at lanes lr, lr+16, lr+32, lr+48
    lsum += __shfl_xor(lsum, 16, 64);
    lsum += __shfl_xor(lsum, 32, 64);
    float inv[4];
#pragma unroll
    for (int r = 0; r < 4; ++r) inv[r] = 1.0f / __shfl(lsum, lg * 4 + r, 64);

#pragma unroll
    for (int t = 0; t < 4; ++t)
#pragma unroll
        for (int r = 0; r < 4; ++r) {
            const int row = qb * 64 + w * 16 + lg * 4 + r;
            float o = Oa[t][r] * inv[r];
            Octx[((size_t)(b * 2048 + row)) * 1024 + h * 64 + t * 16 + lr] = (__bf16)o;
        }
}

// ---------------- launch ----------------
extern "C" void kernel_launch(void* const* d_in, const int* in_sizes, int n_in,
                              void* d_out, int out_size, void* d_ws, size_t ws_size,
                              hipStream_t stream) {
    const float* x         = (const float*)d_in[0];
    const float* attn_bias = (const float*)d_in[1];
    const float* W_qkv     = (const float*)d_in[2];
    const float* q_bias    = (const float*)d_in[3];
    const float* v_bias    = (const float*)d_in[4];
    const float* scale_mul = (const float*)d_in[5];
    const float* W_proj    = (const float*)d_in[6];
    const float* b_proj    = (const float*)d_in[7];
    float* out = (float*)d_out;

    char* ws = (char*)d_ws;
    size_t off = 0;
    auto alloc = [&](size_t bytes) {
        void* p = ws + off;
        off = (off + bytes + 255) & ~(size_t)255;
        return p;
    };
    __bf16* xb      = (__bf16*)alloc((size_t)4096 * 1024 * 2);
    __bf16* wqkvb   = (__bf16*)alloc((size_t)3072 * 1024 * 2);
    __bf16* wprojb  = (__bf16*)alloc((size_t)1024 * 1024 * 2);
    __bf16* Qw      = (__bf16*)alloc((size_t)BB * HH * LL * DD * 2);
    __bf16* Kw      = (__bf16*)alloc((size_t)BB * HH * LL * DD * 2);
    __bf16* Vw      = (__bf16*)alloc((size_t)BB * HH * LL * DD * 2);
    __bf16* Oc      = (__bf16*)alloc((size_t)4096 * 1024 * 2);
    __bf16* bias_bf = (__bf16*)alloc((size_t)2048 * 2048 * 2);
    __bf16* Vt      = (__bf16*)alloc((size_t)BB * HH * LL * DD * 2);

    cvt_bf16_kernel<<<4096, 256, 0, stream>>>(x, xb, 4096 * 1024 / 4);
    cvt_bf16_kernel<<<3072, 256, 0, stream>>>(W_qkv, wqkvb, 3072 * 1024 / 4);
    cvt_bf16_kernel<<<1024, 256, 0, stream>>>(W_proj, wprojb, 1024 * 1024 / 4);

    gemm_qkv_fused_kernel<<<dim3(32, 24), 256, 0, stream>>>(
        xb, wqkvb, q_bias, v_bias, scale_mul, Qw, Kw, Vw);

    bias_prep_kernel<<<2048, 256, 0, stream>>>(attn_bias, bias_bf);
    v_transpose_kernel<<<dim3(32, 32), 256, 0, stream>>>(Vw, Vt);

    attn_kernel<<<dim3(32, 32), 256, 0, stream>>>(Qw, Kw, Vt, bias_bf, scale_mul, Oc);

    gemm_proj_kernel<<<dim3(32, 8), 256, 0, stream>>>(
        Oc, wprojb, out, b_proj, 4096, 1024, 1024);
}

// Round 11
// 206.190 us; speedup vs baseline: 1.2010x; 1.2010x over previous
//
#include <hip/hip_runtime.h>

// Pipeline: cvt(x,Wqkv,Wproj) -> GEMM qkv + fused bias/l2norm/scale/split (Q pre-scaled
//           smh*log2e) -> bias_prep (bias*log2e) -> v_transpose ->
//           flash attn (QBLK=64, swapped-QK^T, bias-in-acc, in-register P,
//                       3-buf gload_lds ring, counted vmcnt, raw s_barrier)
//           -> GEMM proj(f32+bias)
// B=2 L=2048 C=1024 H=16 D=64. All matmuls bf16 MFMA 16x16x32, f32 accumulate.

typedef __bf16 bf16x8 __attribute__((ext_vector_type(8)));
typedef __bf16 bf16x4 __attribute__((ext_vector_type(4)));
typedef float  f32x4  __attribute__((ext_vector_type(4)));

#define BB 2
#define LL 2048
#define CC 1024
#define HH 16
#define DD 64
#define LOG2E 1.44269504088896f

__device__ __forceinline__ f32x4 mfma_16x16x32(bf16x8 a, bf16x8 b, f32x4 c) {
    return __builtin_amdgcn_mfma_f32_16x16x32_bf16(a, b, c, 0, 0, 0);
}

// async global->LDS, 16B per lane; LDS dest = wave-uniform base + lane*16
__device__ __forceinline__ void gload_lds16(const __bf16* g, __bf16* lds) {
    __builtin_amdgcn_global_load_lds(
        (const __attribute__((address_space(1))) unsigned int*)g,
        (__attribute__((address_space(3))) unsigned int*)lds,
        16, 0, 0);
}

__device__ __forceinline__ unsigned pk_bf16(float a, float b) {
    unsigned short ua = __builtin_bit_cast(unsigned short, (__bf16)a);
    unsigned short ub = __builtin_bit_cast(unsigned short, (__bf16)b);
    return (unsigned)ua | ((unsigned)ub << 16);
}

// ---------------- f32 -> bf16 convert ----------------
__global__ __launch_bounds__(256) void cvt_bf16_kernel(const float* __restrict__ in,
                                                       __bf16* __restrict__ out, int n4) {
    int i = blockIdx.x * 256 + threadIdx.x;
    if (i >= n4) return;
    float4 v = reinterpret_cast<const float4*>(in)[i];
    bf16x4 o;
    o[0] = (__bf16)v.x; o[1] = (__bf16)v.y; o[2] = (__bf16)v.z; o[3] = (__bf16)v.w;
    reinterpret_cast<bf16x4*>(out)[i] = o;
}

// ---------------- bias prep: rowmax + bf16((bias - rowmax)*log2e) ----------------
__global__ __launch_bounds__(256) void bias_prep_kernel(const float* __restrict__ bias,
                                                        __bf16* __restrict__ bias_bf) {
    __shared__ float wmax[4];
    const int l = blockIdx.x, tid = threadIdx.x;
    const int w = tid >> 6;
    float4 a = reinterpret_cast<const float4*>(bias + (size_t)l * 2048)[tid];
    float4 b = reinterpret_cast<const float4*>(bias + (size_t)l * 2048 + 1024)[tid];
    float m = fmaxf(fmaxf(fmaxf(a.x, a.y), fmaxf(a.z, a.w)),
                    fmaxf(fmaxf(b.x, b.y), fmaxf(b.z, b.w)));
#pragma unroll
    for (int off = 1; off < 64; off <<= 1) m = fmaxf(m, __shfl_xor(m, off, 64));
    if ((tid & 63) == 0) wmax[w] = m;
    __syncthreads();
    float M = fmaxf(fmaxf(wmax[0], wmax[1]), fmaxf(wmax[2], wmax[3]));
    bf16x4 o0, o1;
    o0[0] = (__bf16)((a.x - M) * LOG2E); o0[1] = (__bf16)((a.y - M) * LOG2E);
    o0[2] = (__bf16)((a.z - M) * LOG2E); o0[3] = (__bf16)((a.w - M) * LOG2E);
    o1[0] = (__bf16)((b.x - M) * LOG2E); o1[1] = (__bf16)((b.y - M) * LOG2E);
    o1[2] = (__bf16)((b.z - M) * LOG2E); o1[3] = (__bf16)((b.w - M) * LOG2E);
    reinterpret_cast<bf16x4*>(bias_bf + (size_t)l * 2048)[tid] = o0;
    reinterpret_cast<bf16x4*>(bias_bf + (size_t)l * 2048 + 1024)[tid] = o1;
}

// ---------------- QKV GEMM + fused bias/l2norm/scale/split ----------------
__global__ __launch_bounds__(256) void gemm_qkv_fused_kernel(
    const __bf16* __restrict__ A, const __bf16* __restrict__ Bm,
    const float* __restrict__ q_bias, const float* __restrict__ v_bias,
    const float* __restrict__ scale_mul,
    __bf16* __restrict__ Qw, __bf16* __restrict__ Kw, __bf16* __restrict__ Vw) {
    __shared__ __bf16 As[128 * 64];   // LDS[row][c] = A[row][c ^ ((row&7)<<4)]  (byte view)
    __shared__ __bf16 Bs[128 * 64];
    const int tid = threadIdx.x;
    const int K = 1024;
    const int nwg = gridDim.x * gridDim.y;
    const int flat = blockIdx.y * gridDim.x + blockIdx.x;
    const int wg = (flat & 7) * (nwg >> 3) + (flat >> 3);
    const int m0 = (wg % gridDim.x) * 128, n0 = (wg / gridDim.x) * 128;
    const int w  = tid >> 6, l = tid & 63;
    const int wr = (w >> 1) * 64, wc = (w & 1) * 64;
    const int lr = l & 15, lg = l >> 4;
    const int rmask = (lr & 7) << 4;
    f32x4 acc[4][4] = {};
    const int lrow = l >> 3;
    const int celem = (((l & 7) ^ lrow) << 3);

    for (int kt = 0; kt < K; kt += 64) {
        __syncthreads();
#pragma unroll
        for (int i = 0; i < 4; ++i) {
            const int row = w * 32 + i * 8;
            gload_lds16(A + (size_t)(m0 + row + lrow) * K + kt + celem, &As[row * 64]);
            gload_lds16(Bm + (size_t)(n0 + row + lrow) * K + kt + celem, &Bs[row * 64]);
        }
        asm volatile("s_waitcnt vmcnt(0)" ::: "memory");
        __syncthreads();
#pragma unroll
        for (int kk = 0; kk < 2; ++kk) {
            bf16x8 af[4], bfr[4];
#pragma unroll
            for (int m = 0; m < 4; ++m)
                af[m] = *reinterpret_cast<const bf16x8*>(
                    (char*)As + (wr + m * 16 + lr) * 128 + ((kk * 64 + lg * 16) ^ rmask));
#pragma unroll
            for (int n = 0; n < 4; ++n)
                bfr[n] = *reinterpret_cast<const bf16x8*>(
                    (char*)Bs + (wc + n * 16 + lr) * 128 + ((kk * 64 + lg * 16) ^ rmask));
#pragma unroll
            for (int m = 0; m < 4; ++m)
#pragma unroll
                for (int n = 0; n < 4; ++n)
                    acc[m][n] = mfma_16x16x32(af[m], bfr[n], acc[m][n]);
        }
    }

    // ---- fused epilogue ----
    const int gcbase = n0 + wc;
    const int type = gcbase >> 10;           // 0=q, 1=k, 2=v
    const int h = (gcbase & 1023) >> 6;
    float qscale = 1.0f;
    if (type == 0) qscale = __expf(fminf(scale_mul[h], 4.60517019f)) * LOG2E;
    __bf16* dst = (type == 0) ? Qw : (type == 1) ? Kw : Vw;

#pragma unroll
    for (int m = 0; m < 4; ++m) {
        if (type != 1) {
            const float* bptr = (type == 0) ? q_bias : v_bias;
#pragma unroll
            for (int n = 0; n < 4; ++n) {
                float bv = bptr[(gcbase & 1023) + n * 16 + lr];
#pragma unroll
                for (int r = 0; r < 4; ++r) acc[m][n][r] += bv;
            }
        }
        float rs[4];
        if (type < 2) {
#pragma unroll
            for (int r = 0; r < 4; ++r) {
                float ss = 0.f;
#pragma unroll
                for (int n = 0; n < 4; ++n) ss += acc[m][n][r] * acc[m][n][r];
                rs[r] = ss;
            }
#pragma unroll
            for (int off = 1; off < 16; off <<= 1)
#pragma unroll
                for (int r = 0; r < 4; ++r) rs[r] += __shfl_xor(rs[r], off, 64);
#pragma unroll
            for (int r = 0; r < 4; ++r)
                rs[r] = ((type == 0) ? qscale : 1.0f) / fmaxf(sqrtf(rs[r]), 1e-12f);
        } else {
#pragma unroll
            for (int r = 0; r < 4; ++r) rs[r] = 1.0f;
        }
        const int rowg = m0 + wr + m * 16 + lg * 4;
#pragma unroll
        for (int n = 0; n < 4; ++n) {
            const int d = n * 16 + lr;
#pragma unroll
            for (int r = 0; r < 4; ++r) {
                const int row = rowg + r;
                const int bb = row >> 11, ll = row & 2047;
                dst[((size_t)((bb << 4) + h) * 2048 + ll) * 64 + d] =
                    (__bf16)(acc[m][n][r] * rs[r]);
            }
        }
    }
}

// ---------------- GEMM proj: C = A*B^T + bias (f32 out), m97 + XCD swz ----------
__global__ __launch_bounds__(256) void gemm_proj_kernel(
    const __bf16* __restrict__ A, const __bf16* __restrict__ Bm,
    float* __restrict__ Cf, const float* __restrict__ bias, int M, int N, int K) {
    __shared__ __bf16 As[128 * 64];
    __shared__ __bf16 Bs[128 * 64];
    const int tid = threadIdx.x;
    const int nwg = gridDim.x * gridDim.y;
    const int flat = blockIdx.y * gridDim.x + blockIdx.x;
    const int wg = (flat & 7) * (nwg >> 3) + (flat >> 3);
    const int m0 = (wg % gridDim.x) * 128, n0 = (wg / gridDim.x) * 128;
    const int w  = tid >> 6, l = tid & 63;
    const int wr = (w >> 1) * 64, wc = (w & 1) * 64;
    const int lr = l & 15, lg = l >> 4;
    const int rmask = (lr & 7) << 4;
    f32x4 acc[4][4] = {};
    const int lrow = l >> 3;
    const int celem = (((l & 7) ^ lrow) << 3);

    for (int kt = 0; kt < K; kt += 64) {
        __syncthreads();
#pragma unroll
        for (int i = 0; i < 4; ++i) {
            const int row = w * 32 + i * 8;
            gload_lds16(A + (size_t)(m0 + row + lrow) * K + kt + celem, &As[row * 64]);
            gload_lds16(Bm + (size_t)(n0 + row + lrow) * K + kt + celem, &Bs[row * 64]);
        }
        asm volatile("s_waitcnt vmcnt(0)" ::: "memory");
        __syncthreads();
#pragma unroll
        for (int kk = 0; kk < 2; ++kk) {
            bf16x8 af[4], bfr[4];
#pragma unroll
            for (int m = 0; m < 4; ++m)
                af[m] = *reinterpret_cast<const bf16x8*>(
                    (char*)As + (wr + m * 16 + lr) * 128 + ((kk * 64 + lg * 16) ^ rmask));
#pragma unroll
            for (int n = 0; n < 4; ++n)
                bfr[n] = *reinterpret_cast<const bf16x8*>(
                    (char*)Bs + (wc + n * 16 + lr) * 128 + ((kk * 64 + lg * 16) ^ rmask));
#pragma unroll
            for (int m = 0; m < 4; ++m)
#pragma unroll
                for (int n = 0; n < 4; ++n)
                    acc[m][n] = mfma_16x16x32(af[m], bfr[n], acc[m][n]);
        }
    }
#pragma unroll
    for (int m = 0; m < 4; ++m)
#pragma unroll
        for (int n = 0; n < 4; ++n) {
            const int row = m0 + wr + m * 16 + lg * 4;
            const int col = n0 + wc + n * 16 + lr;
#pragma unroll
            for (int r = 0; r < 4; ++r)
                Cf[(size_t)(row + r) * N + col] = acc[m][n][r] + bias[col];
        }
}

// ---------------- V transpose: (B,H,L,D) -> (B,H,D,L) ----------------
__global__ __launch_bounds__(256) void v_transpose_kernel(const __bf16* __restrict__ Vin,
                                                          __bf16* __restrict__ Vt) {
    __shared__ __bf16 T[64][72];
    const int lb = blockIdx.x, bh = blockIdx.y;
    const int tid = threadIdx.x;
    const size_t base = (size_t)bh * LL * DD;
    const int row = tid >> 2, c = (tid & 3) * 16;
    {
        const __bf16* src = Vin + base + (size_t)(lb * 64 + row) * 64 + c;
        *reinterpret_cast<bf16x8*>(&T[row][c])     = *reinterpret_cast<const bf16x8*>(src);
        *reinterpret_cast<bf16x8*>(&T[row][c + 8]) = *reinterpret_cast<const bf16x8*>(src + 8);
    }
    __syncthreads();
    bf16x8 o0, o1;
#pragma unroll
    for (int j = 0; j < 8; ++j) {
        o0[j] = T[c + j][row];
        o1[j] = T[c + 8 + j][row];
    }
    __bf16* dst = Vt + base + (size_t)row * 2048 + lb * 64 + c;
    *reinterpret_cast<bf16x8*>(dst)     = o0;
    *reinterpret_cast<bf16x8*>(dst + 8) = o1;
}

// ---------------- flash attention: 3-buf gload_lds ring + counted vmcnt ----------
// grid (bh=32, qb=32); 256 threads = 4 waves; wave w owns q-rows [qb*64+w*16, +16).
// Iter kb: issue bias(kb+1), stage tile kb+2 into buf[(kb+2)%3] via gload_lds,
// compute tile kb from buf[kb%3], then vmcnt(8) (leaves the 8 newest loads in flight)
// + raw s_barrier. ~2 compute phases of latency cover; no full drains in the loop.
__global__ __launch_bounds__(256, 3) void attn_kernel(
    const __bf16* __restrict__ Q, const __bf16* __restrict__ K,
    const __bf16* __restrict__ Vt, const __bf16* __restrict__ biasL,
    const float* __restrict__ scale_mul, __bf16* __restrict__ Octx) {
    __shared__ __bf16 KVs[3][2][64 * 64];   // 48KB ring; LDS[r][c]=G[r][c^((r&7)<<3 elems)]
    const int bh = blockIdx.x, qb = blockIdx.y;
    const int tid = threadIdx.x;
    const int w = tid >> 6, l = tid & 63;
    const int lr = l & 15, lg = l >> 4;
    const int rmask = (lr & 7) << 4;
    const int b = bh >> 4, h = bh & 15;
    const size_t base = (size_t)bh * LL * DD;
    const float smh = __expf(fminf(scale_mul[h], 4.60517019f));
    const float cexp = -smh * LOG2E;

    const int gq = qb * 64 + w * 16 + lr;
    bf16x8 qf[2];
    qf[0] = *reinterpret_cast<const bf16x8*>(Q + base + (size_t)gq * 64 + lg * 8);
    qf[1] = *reinterpret_cast<const bf16x8*>(Q + base + (size_t)gq * 64 + 32 + lg * 8);
    const __bf16* brow = biasL + (size_t)gq * 2048 + lg * 4;

    // staging geometry (gload_lds, pre-swizzled global source; R5-verified)
    const int lrow = l >> 3;                      // 0..7
    const int celem = (((l & 7) ^ lrow) << 3);    // pre-swizzled col (elements)
    auto stage = [&](int buf, int kb_) {
        __bf16* Kd = &KVs[buf][0][0];
        __bf16* Vd = &KVs[buf][1][0];
#pragma unroll
        for (int i = 0; i < 2; ++i) {
            const int row = w * 16 + i * 8;
            gload_lds16(K + base + ((size_t)kb_ * 64 + row + lrow) * 64 + celem, Kd + row * 64);
            gload_lds16(Vt + base + (size_t)(row + lrow) * 2048 + kb_ * 64 + celem, Vd + row * 64);
        }
    };
    auto load_bias = [&](int kb_, bf16x4 (&bv)[4]) {
#pragma unroll
        for (int t = 0; t < 4; ++t)
            bv[t] = *reinterpret_cast<const bf16x4*>(brow + kb_ * 64 + t * 16);
    };

    f32x4 Oa[4] = {};
    float lsum = 0.f;
    bf16x4 bcur[4];

    // prologue: tiles 0,1 staged; bias(0) in regs; leave stage(1)+bias(0) in flight
    stage(0, 0);
    load_bias(0, bcur);
    stage(1, 1);
    asm volatile("s_waitcnt vmcnt(8)" ::: "memory");   // stage(0) done
    __builtin_amdgcn_s_barrier();

#pragma unroll 1
    for (int kb = 0; kb < 32; ++kb) {
        bf16x4 bnext[4];
        if (kb < 31) load_bias(kb + 1, bnext);
        __builtin_amdgcn_sched_barrier(0);             // keep bias issue before stage issue
        if (kb < 30) stage((kb + 2) % 3, kb + 2);

        const char* Kc = (const char*)&KVs[kb % 3][0][0];
        const char* Vc = (const char*)&KVs[kb % 3][1][0];

        // acc init = bias*log2e + cexp  (bias folded into MFMA C-input)
        f32x4 sa[4];
#pragma unroll
        for (int t = 0; t < 4; ++t)
#pragma unroll
            for (int r = 0; r < 4; ++r)
                sa[t][r] = (float)bcur[t][r] + cexp;

        // S^T·log2e : lane holds q=lr, k = 16t+4lg+r
#pragma unroll
        for (int t = 0; t < 4; ++t) {
            const char* kr = Kc + (t * 16 + lr) * 128;
            bf16x8 kf0 = *reinterpret_cast<const bf16x8*>(kr + ((lg * 16) ^ rmask));
            bf16x8 kf1 = *reinterpret_cast<const bf16x8*>(kr + ((64 + lg * 16) ^ rmask));
            sa[t] = mfma_16x16x32(kf0, qf[0], sa[t]);
            sa[t] = mfma_16x16x32(kf1, qf[1], sa[t]);
        }

        // softmax: p = exp2(sa); pack lane-local values into A-operand slots
        float p[4][4];
#pragma unroll
        for (int t = 0; t < 4; ++t)
#pragma unroll
            for (int r = 0; r < 4; ++r) {
                p[t][r] = exp2f(sa[t][r]);
                lsum += p[t][r];
            }
        union Upa { unsigned u[4]; bf16x8 v; } pa0, pa1;
        pa0.u[0] = pk_bf16(p[0][0], p[0][1]); pa0.u[1] = pk_bf16(p[0][2], p[0][3]);
        pa0.u[2] = pk_bf16(p[1][0], p[1][1]); pa0.u[3] = pk_bf16(p[1][2], p[1][3]);
        pa1.u[0] = pk_bf16(p[2][0], p[2][1]); pa1.u[1] = pk_bf16(p[2][2], p[2][3]);
        pa1.u[2] = pk_bf16(p[3][0], p[3][1]); pa1.u[3] = pk_bf16(p[3][2], p[3][3]);

        // O += P·V with permuted k-rows folded into vf addressing (b64 reads)
#pragma unroll
        for (int t = 0; t < 4; ++t) {
            const char* vr = Vc + (t * 16 + lr) * 128;
            union Uv { uint2 d[2]; bf16x8 v; } vf0, vf1;
            vf0.d[0] = *reinterpret_cast<const uint2*>(vr + ((lg * 8) ^ rmask));
            vf0.d[1] = *reinterpret_cast<const uint2*>(vr + ((32 + lg * 8) ^ rmask));
            vf1.d[0] = *reinterpret_cast<const uint2*>(vr + ((64 + lg * 8) ^ rmask));
            vf1.d[1] = *reinterpret_cast<const uint2*>(vr + ((96 + lg * 8) ^ rmask));
            Oa[t] = mfma_16x16x32(pa0.v, vf0.v, Oa[t]);
            Oa[t] = mfma_16x16x32(pa1.v, vf1.v, Oa[t]);
        }

        if (kb < 31) {
#pragma unroll
            for (int t = 0; t < 4; ++t) bcur[t] = bnext[t];
            // counted wait: stage(kb+1) done; bias(kb+1)+stage(kb+2) (8 newest) stay in flight
            if (kb < 30) asm volatile("s_waitcnt vmcnt(8)" ::: "memory");
            else         asm volatile("s_waitcnt vmcnt(4)" ::: "memory");
            __builtin_amdgcn_s_barrier();
        }
    }

    // reduce lsum: partials for q=lr live at lanes lr, lr+16, lr+32, lr+48
    lsum += __shfl_xor(lsum, 16, 64);
    lsum += __shfl_xor(lsum, 32, 64);
    float inv[4];
#pragma unroll
    for (int r = 0; r < 4; ++r) inv[r] = 1.0f / __shfl(lsum, lg * 4 + r, 64);

#pragma unroll
    for (int t = 0; t < 4; ++t)
#pragma unroll
        for (int r = 0; r < 4; ++r) {
            const int row = qb * 64 + w * 16 + lg * 4 + r;
            float o = Oa[t][r] * inv[r];
            Octx[((size_t)(b * 2048 + row)) * 1024 + h * 64 + t * 16 + lr] = (__bf16)o;
        }
}

// ---------------- launch ----------------
extern "C" void kernel_launch(void* const* d_in, const int* in_sizes, int n_in,
                              void* d_out, int out_size, void* d_ws, size_t ws_size,
                              hipStream_t stream) {
    const float* x         = (const float*)d_in[0];
    const float* attn_bias = (const float*)d_in[1];
    const float* W_qkv     = (const float*)d_in[2];
    const float* q_bias    = (const float*)d_in[3];
    const float* v_bias    = (const float*)d_in[4];
    const float* scale_mul = (const float*)d_in[5];
    const float* W_proj    = (const float*)d_in[6];
    const float* b_proj    = (const float*)d_in[7];
    float* out = (float*)d_out;

    char* ws = (char*)d_ws;
    size_t off = 0;
    auto alloc = [&](size_t bytes) {
        void* p = ws + off;
        off = (off + bytes + 255) & ~(size_t)255;
        return p;
    };
    __bf16* xb      = (__bf16*)alloc((size_t)4096 * 1024 * 2);
    __bf16* wqkvb   = (__bf16*)alloc((size_t)3072 * 1024 * 2);
    __bf16* wprojb  = (__bf16*)alloc((size_t)1024 * 1024 * 2);
    __bf16* Qw      = (__bf16*)alloc((size_t)BB * HH * LL * DD * 2);
    __bf16* Kw      = (__bf16*)alloc((size_t)BB * HH * LL * DD * 2);
    __bf16* Vw      = (__bf16*)alloc((size_t)BB * HH * LL * DD * 2);
    __bf16* Oc      = (__bf16*)alloc((size_t)4096 * 1024 * 2);
    __bf16* bias_bf = (__bf16*)alloc((size_t)2048 * 2048 * 2);
    __bf16* Vt      = (__bf16*)alloc((size_t)BB * HH * LL * DD * 2);

    cvt_bf16_kernel<<<4096, 256, 0, stream>>>(x, xb, 4096 * 1024 / 4);
    cvt_bf16_kernel<<<3072, 256, 0, stream>>>(W_qkv, wqkvb, 3072 * 1024 / 4);
    cvt_bf16_kernel<<<1024, 256, 0, stream>>>(W_proj, wprojb, 1024 * 1024 / 4);

    gemm_qkv_fused_kernel<<<dim3(32, 24), 256, 0, stream>>>(
        xb, wqkvb, q_bias, v_bias, scale_mul, Qw, Kw, Vw);

    bias_prep_kernel<<<2048, 256, 0, stream>>>(attn_bias, bias_bf);
    v_transpose_kernel<<<dim3(32, 32), 256, 0, stream>>>(Vw, Vt);

    attn_kernel<<<dim3(32, 32), 256, 0, stream>>>(Qw, Kw, Vt, bias_bf, scale_mul, Oc);

    gemm_proj_kernel<<<dim3(32, 8), 256, 0, stream>>>(
        Oc, wprojb, out, b_proj, 4096, 1024, 1024);
}

// Round 12
// 186.672 us; speedup vs baseline: 1.3266x; 1.1046x over previous
//
#include <hip/hip_runtime.h>

// Pipeline: cvt(x,Wqkv,Wproj) -> GEMM qkv + fused bias/l2norm/scale/split (Q pre-scaled
//           smh*log2e) -> bias_prep (f32 (bias-rowmax)*log2e) -> v_transpose ->
//           flash attn (QBLK=64, swapped-QK^T, f32-bias-as-C-init, no-cexp softmax,
//                       in-register P, MFMA row-sum, reg-staged dbuf, 1 barrier/iter)
//           -> GEMM proj(f32+bias)
// B=2 L=2048 C=1024 H=16 D=64. All matmuls bf16 MFMA 16x16x32, f32 accumulate.

typedef __bf16 bf16x8 __attribute__((ext_vector_type(8)));
typedef __bf16 bf16x4 __attribute__((ext_vector_type(4)));
typedef float  f32x4  __attribute__((ext_vector_type(4)));

#define BB 2
#define LL 2048
#define CC 1024
#define HH 16
#define DD 64
#define LOG2E 1.44269504088896f

__device__ __forceinline__ f32x4 mfma_16x16x32(bf16x8 a, bf16x8 b, f32x4 c) {
    return __builtin_amdgcn_mfma_f32_16x16x32_bf16(a, b, c, 0, 0, 0);
}

// async global->LDS, 16B per lane; LDS dest = wave-uniform base + lane*16
__device__ __forceinline__ void gload_lds16(const __bf16* g, __bf16* lds) {
    __builtin_amdgcn_global_load_lds(
        (const __attribute__((address_space(1))) unsigned int*)g,
        (__attribute__((address_space(3))) unsigned int*)lds,
        16, 0, 0);
}

__device__ __forceinline__ unsigned pk_bf16(float a, float b) {
    unsigned short ua = __builtin_bit_cast(unsigned short, (__bf16)a);
    unsigned short ub = __builtin_bit_cast(unsigned short, (__bf16)b);
    return (unsigned)ua | ((unsigned)ub << 16);
}

// ---------------- f32 -> bf16 convert ----------------
__global__ __launch_bounds__(256) void cvt_bf16_kernel(const float* __restrict__ in,
                                                       __bf16* __restrict__ out, int n4) {
    int i = blockIdx.x * 256 + threadIdx.x;
    if (i >= n4) return;
    float4 v = reinterpret_cast<const float4*>(in)[i];
    bf16x4 o;
    o[0] = (__bf16)v.x; o[1] = (__bf16)v.y; o[2] = (__bf16)v.z; o[3] = (__bf16)v.w;
    reinterpret_cast<bf16x4*>(out)[i] = o;
}

// ---------------- bias prep: rowmax + f32 (bias - rowmax)*log2e ----------------
__global__ __launch_bounds__(256) void bias_prep_kernel(const float* __restrict__ bias,
                                                        float* __restrict__ bias_f) {
    __shared__ float wmax[4];
    const int l = blockIdx.x, tid = threadIdx.x;
    const int w = tid >> 6;
    float4 a = reinterpret_cast<const float4*>(bias + (size_t)l * 2048)[tid];
    float4 b = reinterpret_cast<const float4*>(bias + (size_t)l * 2048 + 1024)[tid];
    float m = fmaxf(fmaxf(fmaxf(a.x, a.y), fmaxf(a.z, a.w)),
                    fmaxf(fmaxf(b.x, b.y), fmaxf(b.z, b.w)));
#pragma unroll
    for (int off = 1; off < 64; off <<= 1) m = fmaxf(m, __shfl_xor(m, off, 64));
    if ((tid & 63) == 0) wmax[w] = m;
    __syncthreads();
    float M = fmaxf(fmaxf(wmax[0], wmax[1]), fmaxf(wmax[2], wmax[3]));
    float4 o0, o1;
    o0.x = (a.x - M) * LOG2E; o0.y = (a.y - M) * LOG2E;
    o0.z = (a.z - M) * LOG2E; o0.w = (a.w - M) * LOG2E;
    o1.x = (b.x - M) * LOG2E; o1.y = (b.y - M) * LOG2E;
    o1.z = (b.z - M) * LOG2E; o1.w = (b.w - M) * LOG2E;
    reinterpret_cast<float4*>(bias_f + (size_t)l * 2048)[tid] = o0;
    reinterpret_cast<float4*>(bias_f + (size_t)l * 2048 + 1024)[tid] = o1;
}

// ---------------- QKV GEMM + fused bias/l2norm/scale/split ----------------
__global__ __launch_bounds__(256) void gemm_qkv_fused_kernel(
    const __bf16* __restrict__ A, const __bf16* __restrict__ Bm,
    const float* __restrict__ q_bias, const float* __restrict__ v_bias,
    const float* __restrict__ scale_mul,
    __bf16* __restrict__ Qw, __bf16* __restrict__ Kw, __bf16* __restrict__ Vw) {
    __shared__ __bf16 As[128 * 64];   // LDS[row][c] = A[row][c ^ ((row&7)<<4)]  (byte view)
    __shared__ __bf16 Bs[128 * 64];
    const int tid = threadIdx.x;
    const int K = 1024;
    const int nwg = gridDim.x * gridDim.y;
    const int flat = blockIdx.y * gridDim.x + blockIdx.x;
    const int wg = (flat & 7) * (nwg >> 3) + (flat >> 3);
    const int m0 = (wg % gridDim.x) * 128, n0 = (wg / gridDim.x) * 128;
    const int w  = tid >> 6, l = tid & 63;
    const int wr = (w >> 1) * 64, wc = (w & 1) * 64;
    const int lr = l & 15, lg = l >> 4;
    const int rmask = (lr & 7) << 4;
    f32x4 acc[4][4] = {};
    const int lrow = l >> 3;
    const int celem = (((l & 7) ^ lrow) << 3);

    for (int kt = 0; kt < K; kt += 64) {
        __syncthreads();
#pragma unroll
        for (int i = 0; i < 4; ++i) {
            const int row = w * 32 + i * 8;
            gload_lds16(A + (size_t)(m0 + row + lrow) * K + kt + celem, &As[row * 64]);
            gload_lds16(Bm + (size_t)(n0 + row + lrow) * K + kt + celem, &Bs[row * 64]);
        }
        asm volatile("s_waitcnt vmcnt(0)" ::: "memory");
        __syncthreads();
#pragma unroll
        for (int kk = 0; kk < 2; ++kk) {
            bf16x8 af[4], bfr[4];
#pragma unroll
            for (int m = 0; m < 4; ++m)
                af[m] = *reinterpret_cast<const bf16x8*>(
                    (char*)As + (wr + m * 16 + lr) * 128 + ((kk * 64 + lg * 16) ^ rmask));
#pragma unroll
            for (int n = 0; n < 4; ++n)
                bfr[n] = *reinterpret_cast<const bf16x8*>(
                    (char*)Bs + (wc + n * 16 + lr) * 128 + ((kk * 64 + lg * 16) ^ rmask));
#pragma unroll
            for (int m = 0; m < 4; ++m)
#pragma unroll
                for (int n = 0; n < 4; ++n)
                    acc[m][n] = mfma_16x16x32(af[m], bfr[n], acc[m][n]);
        }
    }

    // ---- fused epilogue ----
    const int gcbase = n0 + wc;
    const int type = gcbase >> 10;           // 0=q, 1=k, 2=v
    const int h = (gcbase & 1023) >> 6;
    float qscale = 1.0f;
    if (type == 0) qscale = __expf(fminf(scale_mul[h], 4.60517019f)) * LOG2E;
    __bf16* dst = (type == 0) ? Qw : (type == 1) ? Kw : Vw;

#pragma unroll
    for (int m = 0; m < 4; ++m) {
        if (type != 1) {
            const float* bptr = (type == 0) ? q_bias : v_bias;
#pragma unroll
            for (int n = 0; n < 4; ++n) {
                float bv = bptr[(gcbase & 1023) + n * 16 + lr];
#pragma unroll
                for (int r = 0; r < 4; ++r) acc[m][n][r] += bv;
            }
        }
        float rs[4];
        if (type < 2) {
#pragma unroll
            for (int r = 0; r < 4; ++r) {
                float ss = 0.f;
#pragma unroll
                for (int n = 0; n < 4; ++n) ss += acc[m][n][r] * acc[m][n][r];
                rs[r] = ss;
            }
#pragma unroll
            for (int off = 1; off < 16; off <<= 1)
#pragma unroll
                for (int r = 0; r < 4; ++r) rs[r] += __shfl_xor(rs[r], off, 64);
#pragma unroll
            for (int r = 0; r < 4; ++r)
                rs[r] = ((type == 0) ? qscale : 1.0f) / fmaxf(sqrtf(rs[r]), 1e-12f);
        } else {
#pragma unroll
            for (int r = 0; r < 4; ++r) rs[r] = 1.0f;
        }
        const int rowg = m0 + wr + m * 16 + lg * 4;
#pragma unroll
        for (int n = 0; n < 4; ++n) {
            const int d = n * 16 + lr;
#pragma unroll
            for (int r = 0; r < 4; ++r) {
                const int row = rowg + r;
                const int bb = row >> 11, ll = row & 2047;
                dst[((size_t)((bb << 4) + h) * 2048 + ll) * 64 + d] =
                    (__bf16)(acc[m][n][r] * rs[r]);
            }
        }
    }
}

// ---------------- GEMM proj: C = A*B^T + bias (f32 out), m97 + XCD swz ----------
__global__ __launch_bounds__(256) void gemm_proj_kernel(
    const __bf16* __restrict__ A, const __bf16* __restrict__ Bm,
    float* __restrict__ Cf, const float* __restrict__ bias, int M, int N, int K) {
    __shared__ __bf16 As[128 * 64];
    __shared__ __bf16 Bs[128 * 64];
    const int tid = threadIdx.x;
    const int nwg = gridDim.x * gridDim.y;
    const int flat = blockIdx.y * gridDim.x + blockIdx.x;
    const int wg = (flat & 7) * (nwg >> 3) + (flat >> 3);
    const int m0 = (wg % gridDim.x) * 128, n0 = (wg / gridDim.x) * 128;
    const int w  = tid >> 6, l = tid & 63;
    const int wr = (w >> 1) * 64, wc = (w & 1) * 64;
    const int lr = l & 15, lg = l >> 4;
    const int rmask = (lr & 7) << 4;
    f32x4 acc[4][4] = {};
    const int lrow = l >> 3;
    const int celem = (((l & 7) ^ lrow) << 3);

    for (int kt = 0; kt < K; kt += 64) {
        __syncthreads();
#pragma unroll
        for (int i = 0; i < 4; ++i) {
            const int row = w * 32 + i * 8;
            gload_lds16(A + (size_t)(m0 + row + lrow) * K + kt + celem, &As[row * 64]);
            gload_lds16(Bm + (size_t)(n0 + row + lrow) * K + kt + celem, &Bs[row * 64]);
        }
        asm volatile("s_waitcnt vmcnt(0)" ::: "memory");
        __syncthreads();
#pragma unroll
        for (int kk = 0; kk < 2; ++kk) {
            bf16x8 af[4], bfr[4];
#pragma unroll
            for (int m = 0; m < 4; ++m)
                af[m] = *reinterpret_cast<const bf16x8*>(
                    (char*)As + (wr + m * 16 + lr) * 128 + ((kk * 64 + lg * 16) ^ rmask));
#pragma unroll
            for (int n = 0; n < 4; ++n)
                bfr[n] = *reinterpret_cast<const bf16x8*>(
                    (char*)Bs + (wc + n * 16 + lr) * 128 + ((kk * 64 + lg * 16) ^ rmask));
#pragma unroll
            for (int m = 0; m < 4; ++m)
#pragma unroll
                for (int n = 0; n < 4; ++n)
                    acc[m][n] = mfma_16x16x32(af[m], bfr[n], acc[m][n]);
        }
    }
#pragma unroll
    for (int m = 0; m < 4; ++m)
#pragma unroll
        for (int n = 0; n < 4; ++n) {
            const int row = m0 + wr + m * 16 + lg * 4;
            const int col = n0 + wc + n * 16 + lr;
#pragma unroll
            for (int r = 0; r < 4; ++r)
                Cf[(size_t)(row + r) * N + col] = acc[m][n][r] + bias[col];
        }
}

// ---------------- V transpose: (B,H,L,D) -> (B,H,D,L) ----------------
__global__ __launch_bounds__(256) void v_transpose_kernel(const __bf16* __restrict__ Vin,
                                                          __bf16* __restrict__ Vt) {
    __shared__ __bf16 T[64][72];
    const int lb = blockIdx.x, bh = blockIdx.y;
    const int tid = threadIdx.x;
    const size_t base = (size_t)bh * LL * DD;
    const int row = tid >> 2, c = (tid & 3) * 16;
    {
        const __bf16* src = Vin + base + (size_t)(lb * 64 + row) * 64 + c;
        *reinterpret_cast<bf16x8*>(&T[row][c])     = *reinterpret_cast<const bf16x8*>(src);
        *reinterpret_cast<bf16x8*>(&T[row][c + 8]) = *reinterpret_cast<const bf16x8*>(src + 8);
    }
    __syncthreads();
    bf16x8 o0, o1;
#pragma unroll
    for (int j = 0; j < 8; ++j) {
        o0[j] = T[c + j][row];
        o1[j] = T[c + 8 + j][row];
    }
    __bf16* dst = Vt + base + (size_t)row * 2048 + lb * 64 + c;
    *reinterpret_cast<bf16x8*>(dst)     = o0;
    *reinterpret_cast<bf16x8*>(dst + 8) = o1;
}

// ---------------- flash attention: R8 structure, f32-bias C-init, no cexp,
//                  in-register P (k-permutation), MFMA row-sum, reg-staged dbuf ----------
// grid (bh=32, qb=32); 256 threads = 4 waves; wave w owns q-rows [qb*64+w*16, +16).
// Softmax scale-invariance: p = exp2(S*log2e + bias'); the per-head constant 2^cexp
// cancels in O = sum(p*v)/sum(p), so it is omitted entirely.
__global__ __launch_bounds__(256, 4) void attn_kernel(
    const __bf16* __restrict__ Q, const __bf16* __restrict__ K,
    const __bf16* __restrict__ Vt, const float* __restrict__ biasF,
    __bf16* __restrict__ Octx) {
    __shared__ __bf16 KVs[2][2][64 * 64];   // [buf][K/V]; LDS[row][c]=G[row][c^((row&7)<<4)]
    const int bh = blockIdx.x, qb = blockIdx.y;
    const int tid = threadIdx.x;
    const int w = tid >> 6, l = tid & 63;
    const int lr = l & 15, lg = l >> 4;
    const int rmask = (lr & 7) << 4;
    const int b = bh >> 4, h = bh & 15;
    const size_t base = (size_t)bh * LL * DD;

    const int gq = qb * 64 + w * 16 + lr;
    bf16x8 qf[2];
    qf[0] = *reinterpret_cast<const bf16x8*>(Q + base + (size_t)gq * 64 + lg * 8);
    qf[1] = *reinterpret_cast<const bf16x8*>(Q + base + (size_t)gq * 64 + 32 + lg * 8);
    const float* brow = biasF + (size_t)gq * 2048 + lg * 4;

    // ones B-operand for MFMA row-sum
    bf16x8 ones;
#pragma unroll
    for (int j = 0; j < 8; ++j) ones[j] = (__bf16)1.0f;

    const int srow = tid >> 2;
    const int scb  = (tid & 3) * 32;
    const int smask = (srow & 7) << 4;
    const __bf16* kgbase = K  + base + (size_t)srow * 64   + (tid & 3) * 16;
    const __bf16* vgbase = Vt + base + (size_t)srow * 2048 + (tid & 3) * 16;

    bf16x8 k0, k1, v0, v1;
    auto stage_regs = [&](int kb) {
        const __bf16* kg = kgbase + (size_t)kb * 64 * 64;
        k0 = *reinterpret_cast<const bf16x8*>(kg);
        k1 = *reinterpret_cast<const bf16x8*>(kg + 8);
        const __bf16* vg = vgbase + kb * 64;
        v0 = *reinterpret_cast<const bf16x8*>(vg);
        v1 = *reinterpret_cast<const bf16x8*>(vg + 8);
    };
    auto write_lds = [&](int buf) {
        char* kp = (char*)KVs[buf][0] + srow * 128;
        char* vp = (char*)KVs[buf][1] + srow * 128;
        *reinterpret_cast<bf16x8*>(kp + (scb ^ smask))        = k0;
        *reinterpret_cast<bf16x8*>(kp + ((scb + 16) ^ smask)) = k1;
        *reinterpret_cast<bf16x8*>(vp + (scb ^ smask))        = v0;
        *reinterpret_cast<bf16x8*>(vp + ((scb + 16) ^ smask)) = v1;
    };

    stage_regs(0);
    write_lds(0);

    f32x4 Oa[4] = {};
    f32x4 ls = {};          // MFMA row-sum accumulator (rows align with Oa rows)
    int cur = 0;

    f32x4 bcur[4];
#pragma unroll
    for (int t = 0; t < 4; ++t)
        bcur[t] = *reinterpret_cast<const f32x4*>(brow + t * 16);

    for (int kb = 0; kb < 32; ++kb) {
        __syncthreads();                    // buf[cur] published; buf[cur^1] free
        if (kb < 31) stage_regs(kb + 1);    // issue next-tile global loads early (T14)

        f32x4 bnext[4];
        if (kb < 31) {
#pragma unroll
            for (int t = 0; t < 4; ++t)
                bnext[t] = *reinterpret_cast<const f32x4*>(brow + (kb + 1) * 64 + t * 16);
        }

        const char* Kc = (const char*)KVs[cur][0];
        const char* Vc = (const char*)KVs[cur][1];

        // S^T·log2e + bias' : C-init = f32 bias (no VALU); lane q=lr, k=16t+4lg+r
        f32x4 sa[4];
#pragma unroll
        for (int t = 0; t < 4; ++t) sa[t] = bcur[t];
#pragma unroll
        for (int t = 0; t < 4; ++t) {
            const char* kr = Kc + (t * 16 + lr) * 128;
            bf16x8 kf0 = *reinterpret_cast<const bf16x8*>(kr + ((lg * 16) ^ rmask));
            bf16x8 kf1 = *reinterpret_cast<const bf16x8*>(kr + ((64 + lg * 16) ^ rmask));
            sa[t] = mfma_16x16x32(kf0, qf[0], sa[t]);
            sa[t] = mfma_16x16x32(kf1, qf[1], sa[t]);
        }

        // softmax: p = exp2(sa); pack lane-local values into A-operand slots
        float p[4][4];
#pragma unroll
        for (int t = 0; t < 4; ++t)
#pragma unroll
            for (int r = 0; r < 4; ++r)
                p[t][r] = exp2f(sa[t][r]);
        union Upa { unsigned u[4]; bf16x8 v; } pa0, pa1;
        pa0.u[0] = pk_bf16(p[0][0], p[0][1]); pa0.u[1] = pk_bf16(p[0][2], p[0][3]);
        pa0.u[2] = pk_bf16(p[1][0], p[1][1]); pa0.u[3] = pk_bf16(p[1][2], p[1][3]);
        pa1.u[0] = pk_bf16(p[2][0], p[2][1]); pa1.u[1] = pk_bf16(p[2][2], p[2][3]);
        pa1.u[2] = pk_bf16(p[3][0], p[3][1]); pa1.u[3] = pk_bf16(p[3][2], p[3][3]);

        // row-sum via MFMA (B = ones): ls rows = q rows, same layout as Oa
        ls = mfma_16x16x32(pa0.v, ones, ls);
        ls = mfma_16x16x32(pa1.v, ones, ls);

        // O += P·V with permuted k-rows folded into vf addressing (b64 reads)
#pragma unroll
        for (int t = 0; t < 4; ++t) {
            const char* vr = Vc + (t * 16 + lr) * 128;
            union Uv { uint2 d[2]; bf16x8 v; } vf0, vf1;
            vf0.d[0] = *reinterpret_cast<const uint2*>(vr + ((lg * 8) ^ rmask));
            vf0.d[1] = *reinterpret_cast<const uint2*>(vr + ((32 + lg * 8) ^ rmask));
            vf1.d[0] = *reinterpret_cast<const uint2*>(vr + ((64 + lg * 8) ^ rmask));
            vf1.d[1] = *reinterpret_cast<const uint2*>(vr + ((96 + lg * 8) ^ rmask));
            Oa[t] = mfma_16x16x32(pa0.v, vf0.v, Oa[t]);
            Oa[t] = mfma_16x16x32(pa1.v, vf1.v, Oa[t]);
        }

        if (kb < 31) {
            write_lds(cur ^ 1);             // write-late; dep on loads forces vmcnt
#pragma unroll
            for (int t = 0; t < 4; ++t) bcur[t] = bnext[t];
        }
        cur ^= 1;
    }

    // inv directly from MFMA row-sum (no shuffles: ls rows == Oa rows)
    float inv[4];
#pragma unroll
    for (int r = 0; r < 4; ++r) inv[r] = 1.0f / ls[r];

#pragma unroll
    for (int t = 0; t < 4; ++t)
#pragma unroll
        for (int r = 0; r < 4; ++r) {
            const int row = qb * 64 + w * 16 + lg * 4 + r;
            float o = Oa[t][r] * inv[r];
            Octx[((size_t)(b * 2048 + row)) * 1024 + h * 64 + t * 16 + lr] = (__bf16)o;
        }
}

// ---------------- launch ----------------
extern "C" void kernel_launch(void* const* d_in, const int* in_sizes, int n_in,
                              void* d_out, int out_size, void* d_ws, size_t ws_size,
                              hipStream_t stream) {
    const float* x         = (const float*)d_in[0];
    const float* attn_bias = (const float*)d_in[1];
    const float* W_qkv     = (const float*)d_in[2];
    const float* q_bias    = (const float*)d_in[3];
    const float* v_bias    = (const float*)d_in[4];
    const float* scale_mul = (const float*)d_in[5];
    const float* W_proj    = (const float*)d_in[6];
    const float* b_proj    = (const float*)d_in[7];
    float* out = (float*)d_out;

    char* ws = (char*)d_ws;
    size_t off = 0;
    auto alloc = [&](size_t bytes) {
        void* p = ws + off;
        off = (off + bytes + 255) & ~(size_t)255;
        return p;
    };
    __bf16* xb      = (__bf16*)alloc((size_t)4096 * 1024 * 2);
    __bf16* wqkvb   = (__bf16*)alloc((size_t)3072 * 1024 * 2);
    __bf16* wprojb  = (__bf16*)alloc((size_t)1024 * 1024 * 2);
    __bf16* Qw      = (__bf16*)alloc((size_t)BB * HH * LL * DD * 2);
    __bf16* Kw      = (__bf16*)alloc((size_t)BB * HH * LL * DD * 2);
    __bf16* Vw      = (__bf16*)alloc((size_t)BB * HH * LL * DD * 2);
    __bf16* Oc      = (__bf16*)alloc((size_t)4096 * 1024 * 2);
    float*  bias_f  = (float*)alloc((size_t)2048 * 2048 * 4);   // 16 MB f32
    __bf16* Vt      = (__bf16*)alloc((size_t)BB * HH * LL * DD * 2);

    cvt_bf16_kernel<<<4096, 256, 0, stream>>>(x, xb, 4096 * 1024 / 4);
    cvt_bf16_kernel<<<3072, 256, 0, stream>>>(W_qkv, wqkvb, 3072 * 1024 / 4);
    cvt_bf16_kernel<<<1024, 256, 0, stream>>>(W_proj, wprojb, 1024 * 1024 / 4);

    gemm_qkv_fused_kernel<<<dim3(32, 24), 256, 0, stream>>>(
        xb, wqkvb, q_bias, v_bias, scale_mul, Qw, Kw, Vw);

    bias_prep_kernel<<<2048, 256, 0, stream>>>(attn_bias, bias_f);
    v_transpose_kernel<<<dim3(32, 32), 256, 0, stream>>>(Vw, Vt);

    attn_kernel<<<dim3(32, 32), 256, 0, stream>>>(Qw, Kw, Vt, bias_f, Oc);

    gemm_proj_kernel<<<dim3(32, 8), 256, 0, stream>>>(
        Oc, wprojb, out, b_proj, 4096, 1024, 1024);
}

// Round 14
// 185.119 us; speedup vs baseline: 1.3377x; 1.0084x over previous
//
#include <hip/hip_runtime.h>

// Pipeline: cvt(x,Wqkv,Wproj) -> GEMM qkv + fused bias/l2norm/scale/split (Q pre-scaled
//           smh*log2e) -> bias_prep (bf16 (bias-rowmax)*log2e) -> v_transpose (+k-perm) ->
//           flash attn (8 waves/block QBLK=128, KV-split x2, swapped-QK^T, bias C-init,
//                       in-register P, MFMA row-sum, reg-staged dbuf, 1 barrier/iter)
//           -> combine partials -> GEMM proj(f32+bias)
// B=2 L=2048 C=1024 H=16 D=64. All matmuls bf16 MFMA 16x16x32, f32 accumulate.

typedef __bf16 bf16x8 __attribute__((ext_vector_type(8)));
typedef __bf16 bf16x4 __attribute__((ext_vector_type(4)));
typedef float  f32x4  __attribute__((ext_vector_type(4)));

#define BB 2
#define LL 2048
#define CC 1024
#define HH 16
#define DD 64
#define LOG2E 1.44269504088896f

__device__ __forceinline__ f32x4 mfma_16x16x32(bf16x8 a, bf16x8 b, f32x4 c) {
    return __builtin_amdgcn_mfma_f32_16x16x32_bf16(a, b, c, 0, 0, 0);
}

// async global->LDS, 16B per lane; LDS dest = wave-uniform base + lane*16
__device__ __forceinline__ void gload_lds16(const __bf16* g, __bf16* lds) {
    __builtin_amdgcn_global_load_lds(
        (const __attribute__((address_space(1))) unsigned int*)g,
        (__attribute__((address_space(3))) unsigned int*)lds,
        16, 0, 0);
}

__device__ __forceinline__ unsigned pk_bf16(float a, float b) {
    unsigned short ua = __builtin_bit_cast(unsigned short, (__bf16)a);
    unsigned short ub = __builtin_bit_cast(unsigned short, (__bf16)b);
    return (unsigned)ua | ((unsigned)ub << 16);
}

// ---------------- f32 -> bf16 convert ----------------
__global__ __launch_bounds__(256) void cvt_bf16_kernel(const float* __restrict__ in,
                                                       __bf16* __restrict__ out, int n4) {
    int i = blockIdx.x * 256 + threadIdx.x;
    if (i >= n4) return;
    float4 v = reinterpret_cast<const float4*>(in)[i];
    bf16x4 o;
    o[0] = (__bf16)v.x; o[1] = (__bf16)v.y; o[2] = (__bf16)v.z; o[3] = (__bf16)v.w;
    reinterpret_cast<bf16x4*>(out)[i] = o;
}

// ---------------- bias prep: rowmax + bf16((bias - rowmax)*log2e) ----------------
__global__ __launch_bounds__(256) void bias_prep_kernel(const float* __restrict__ bias,
                                                        __bf16* __restrict__ bias_bf) {
    __shared__ float wmax[4];
    const int l = blockIdx.x, tid = threadIdx.x;
    const int w = tid >> 6;
    float4 a = reinterpret_cast<const float4*>(bias + (size_t)l * 2048)[tid];
    float4 b = reinterpret_cast<const float4*>(bias + (size_t)l * 2048 + 1024)[tid];
    float m = fmaxf(fmaxf(fmaxf(a.x, a.y), fmaxf(a.z, a.w)),
                    fmaxf(fmaxf(b.x, b.y), fmaxf(b.z, b.w)));
#pragma unroll
    for (int off = 1; off < 64; off <<= 1) m = fmaxf(m, __shfl_xor(m, off, 64));
    if ((tid & 63) == 0) wmax[w] = m;
    __syncthreads();
    float M = fmaxf(fmaxf(wmax[0], wmax[1]), fmaxf(wmax[2], wmax[3]));
    bf16x4 o0, o1;
    o0[0] = (__bf16)((a.x - M) * LOG2E); o0[1] = (__bf16)((a.y - M) * LOG2E);
    o0[2] = (__bf16)((a.z - M) * LOG2E); o0[3] = (__bf16)((a.w - M) * LOG2E);
    o1[0] = (__bf16)((b.x - M) * LOG2E); o1[1] = (__bf16)((b.y - M) * LOG2E);
    o1[2] = (__bf16)((b.z - M) * LOG2E); o1[3] = (__bf16)((b.w - M) * LOG2E);
    reinterpret_cast<bf16x4*>(bias_bf + (size_t)l * 2048)[tid] = o0;
    reinterpret_cast<bf16x4*>(bias_bf + (size_t)l * 2048 + 1024)[tid] = o1;
}

// ---------------- QKV GEMM + fused bias/l2norm/scale/split ----------------
__global__ __launch_bounds__(256) void gemm_qkv_fused_kernel(
    const __bf16* __restrict__ A, const __bf16* __restrict__ Bm,
    const float* __restrict__ q_bias, const float* __restrict__ v_bias,
    const float* __restrict__ scale_mul,
    __bf16* __restrict__ Qw, __bf16* __restrict__ Kw, __bf16* __restrict__ Vw) {
    __shared__ __bf16 As[128 * 64];   // LDS[row][c] = A[row][c ^ ((row&7)<<4)]  (byte view)
    __shared__ __bf16 Bs[128 * 64];
    const int tid = threadIdx.x;
    const int K = 1024;
    const int nwg = gridDim.x * gridDim.y;
    const int flat = blockIdx.y * gridDim.x + blockIdx.x;
    const int wg = (flat & 7) * (nwg >> 3) + (flat >> 3);
    const int m0 = (wg % gridDim.x) * 128, n0 = (wg / gridDim.x) * 128;
    const int w  = tid >> 6, l = tid & 63;
    const int wr = (w >> 1) * 64, wc = (w & 1) * 64;
    const int lr = l & 15, lg = l >> 4;
    const int rmask = (lr & 7) << 4;
    f32x4 acc[4][4] = {};
    const int lrow = l >> 3;
    const int celem = (((l & 7) ^ lrow) << 3);

    for (int kt = 0; kt < K; kt += 64) {
        __syncthreads();
#pragma unroll
        for (int i = 0; i < 4; ++i) {
            const int row = w * 32 + i * 8;
            gload_lds16(A + (size_t)(m0 + row + lrow) * K + kt + celem, &As[row * 64]);
            gload_lds16(Bm + (size_t)(n0 + row + lrow) * K + kt + celem, &Bs[row * 64]);
        }
        asm volatile("s_waitcnt vmcnt(0)" ::: "memory");
        __syncthreads();
#pragma unroll
        for (int kk = 0; kk < 2; ++kk) {
            bf16x8 af[4], bfr[4];
#pragma unroll
            for (int m = 0; m < 4; ++m)
                af[m] = *reinterpret_cast<const bf16x8*>(
                    (char*)As + (wr + m * 16 + lr) * 128 + ((kk * 64 + lg * 16) ^ rmask));
#pragma unroll
            for (int n = 0; n < 4; ++n)
                bfr[n] = *reinterpret_cast<const bf16x8*>(
                    (char*)Bs + (wc + n * 16 + lr) * 128 + ((kk * 64 + lg * 16) ^ rmask));
#pragma unroll
            for (int m = 0; m < 4; ++m)
#pragma unroll
                for (int n = 0; n < 4; ++n)
                    acc[m][n] = mfma_16x16x32(af[m], bfr[n], acc[m][n]);
        }
    }

    // ---- fused epilogue ----
    const int gcbase = n0 + wc;
    const int type = gcbase >> 10;           // 0=q, 1=k, 2=v
    const int h = (gcbase & 1023) >> 6;
    float qscale = 1.0f;
    if (type == 0) qscale = __expf(fminf(scale_mul[h], 4.60517019f)) * LOG2E;
    __bf16* dst = (type == 0) ? Qw : (type == 1) ? Kw : Vw;

#pragma unroll
    for (int m = 0; m < 4; ++m) {
        if (type != 1) {
            const float* bptr = (type == 0) ? q_bias : v_bias;
#pragma unroll
            for (int n = 0; n < 4; ++n) {
                float bv = bptr[(gcbase & 1023) + n * 16 + lr];
#pragma unroll
                for (int r = 0; r < 4; ++r) acc[m][n][r] += bv;
            }
        }
        float rs[4];
        if (type < 2) {
#pragma unroll
            for (int r = 0; r < 4; ++r) {
                float ss = 0.f;
#pragma unroll
                for (int n = 0; n < 4; ++n) ss += acc[m][n][r] * acc[m][n][r];
                rs[r] = ss;
            }
#pragma unroll
            for (int off = 1; off < 16; off <<= 1)
#pragma unroll
                for (int r = 0; r < 4; ++r) rs[r] += __shfl_xor(rs[r], off, 64);
#pragma unroll
            for (int r = 0; r < 4; ++r)
                rs[r] = ((type == 0) ? qscale : 1.0f) / fmaxf(sqrtf(rs[r]), 1e-12f);
        } else {
#pragma unroll
            for (int r = 0; r < 4; ++r) rs[r] = 1.0f;
        }
        const int rowg = m0 + wr + m * 16 + lg * 4;
#pragma unroll
        for (int n = 0; n < 4; ++n) {
            const int d = n * 16 + lr;
#pragma unroll
            for (int r = 0; r < 4; ++r) {
                const int row = rowg + r;
                const int bb = row >> 11, ll = row & 2047;
                dst[((size_t)((bb << 4) + h) * 2048 + ll) * 64 + d] =
                    (__bf16)(acc[m][n][r] * rs[r]);
            }
        }
    }
}

// ---------------- GEMM proj: C = A*B^T + bias (f32 out), m97 + XCD swz ----------
__global__ __launch_bounds__(256) void gemm_proj_kernel(
    const __bf16* __restrict__ A, const __bf16* __restrict__ Bm,
    float* __restrict__ Cf, const float* __restrict__ bias, int M, int N, int K) {
    __shared__ __bf16 As[128 * 64];
    __shared__ __bf16 Bs[128 * 64];
    const int tid = threadIdx.x;
    const int nwg = gridDim.x * gridDim.y;
    const int flat = blockIdx.y * gridDim.x + blockIdx.x;
    const int wg = (flat & 7) * (nwg >> 3) + (flat >> 3);
    const int m0 = (wg % gridDim.x) * 128, n0 = (wg / gridDim.x) * 128;
    const int w  = tid >> 6, l = tid & 63;
    const int wr = (w >> 1) * 64, wc = (w & 1) * 64;
    const int lr = l & 15, lg = l >> 4;
    const int rmask = (lr & 7) << 4;
    f32x4 acc[4][4] = {};
    const int lrow = l >> 3;
    const int celem = (((l & 7) ^ lrow) << 3);

    for (int kt = 0; kt < K; kt += 64) {
        __syncthreads();
#pragma unroll
        for (int i = 0; i < 4; ++i) {
            const int row = w * 32 + i * 8;
            gload_lds16(A + (size_t)(m0 + row + lrow) * K + kt + celem, &As[row * 64]);
            gload_lds16(Bm + (size_t)(n0 + row + lrow) * K + kt + celem, &Bs[row * 64]);
        }
        asm volatile("s_waitcnt vmcnt(0)" ::: "memory");
        __syncthreads();
#pragma unroll
        for (int kk = 0; kk < 2; ++kk) {
            bf16x8 af[4], bfr[4];
#pragma unroll
            for (int m = 0; m < 4; ++m)
                af[m] = *reinterpret_cast<const bf16x8*>(
                    (char*)As + (wr + m * 16 + lr) * 128 + ((kk * 64 + lg * 16) ^ rmask));
#pragma unroll
            for (int n = 0; n < 4; ++n)
                bfr[n] = *reinterpret_cast<const bf16x8*>(
                    (char*)Bs + (wc + n * 16 + lr) * 128 + ((kk * 64 + lg * 16) ^ rmask));
#pragma unroll
            for (int m = 0; m < 4; ++m)
#pragma unroll
                for (int n = 0; n < 4; ++n)
                    acc[m][n] = mfma_16x16x32(af[m], bfr[n], acc[m][n]);
        }
    }
#pragma unroll
    for (int m = 0; m < 4; ++m)
#pragma unroll
        for (int n = 0; n < 4; ++n) {
            const int row = m0 + wr + m * 16 + lg * 4;
            const int col = n0 + wc + n * 16 + lr;
#pragma unroll
            for (int r = 0; r < 4; ++r)
                Cf[(size_t)(row + r) * N + col] = acc[m][n][r] + bias[col];
        }
}

// ---------------- V transpose + k-permutation: (B,H,L,D) -> (B,H,D,perm(L)) ----------
// Within each 32-col block, col c' stores original k = 16*c'[2] + 4*c'[4:3] + c'[1:0],
// so attn's in-register P slot order matches contiguous b128 reads.
__global__ __launch_bounds__(256) void v_transpose_kernel(const __bf16* __restrict__ Vin,
                                                          __bf16* __restrict__ Vp) {
    __shared__ __bf16 T[64][72];
    const int lb = blockIdx.x, bh = blockIdx.y;
    const int tid = threadIdx.x;
    const size_t base = (size_t)bh * LL * DD;
    const int row = tid >> 2, c = (tid & 3) * 16;
    {
        const __bf16* src = Vin + base + (size_t)(lb * 64 + row) * 64 + c;
        *reinterpret_cast<bf16x8*>(&T[row][c])     = *reinterpret_cast<const bf16x8*>(src);
        *reinterpret_cast<bf16x8*>(&T[row][c + 8]) = *reinterpret_cast<const bf16x8*>(src + 8);
    }
    __syncthreads();
    __bf16 val[16];
#pragma unroll
    for (int jj = 0; jj < 16; ++jj) {
        const int cp = c + jj;
        const int wb = cp & 31;
        const int kloc = (cp & ~31) | (((wb >> 3) & 3) << 2) | (((wb >> 2) & 1) << 4) | (wb & 3);
        val[jj] = T[kloc][row];
    }
    __bf16* dst = Vp + base + (size_t)row * 2048 + lb * 64 + c;
    *reinterpret_cast<bf16x8*>(dst)     = *reinterpret_cast<bf16x8*>(&val[0]);
    *reinterpret_cast<bf16x8*>(dst + 8) = *reinterpret_cast<bf16x8*>(&val[8]);
}

// ---------------- flash attention: 8 waves (512 thr), QBLK=128, KV-split x2 ----------
// grid (bh=32, qb=16, sp=2); wave w owns q-rows [qb*128+w*16, +16); each split covers
// 16 kb-tiles. Fixed-max softmax (no per-split max) => partials combine by pure addition.
__global__ __launch_bounds__(512, 6) void attn_kernel(
    const __bf16* __restrict__ Q, const __bf16* __restrict__ K,
    const __bf16* __restrict__ Vp, const __bf16* __restrict__ biasB,
    float* __restrict__ Of0, float* __restrict__ Of1, float* __restrict__ lsF) {
    __shared__ __bf16 KVs[2][2][64 * 64];   // [buf][K/V]; LDS[row][c]=G[row][c^((row&7)<<4)]
    const int bh = blockIdx.x, qb = blockIdx.y, sp = blockIdx.z;
    const int tid = threadIdx.x;
    const int w = tid >> 6, l = tid & 63;
    const int lr = l & 15, lg = l >> 4;
    const int rmask = (lr & 7) << 4;
    const int b = bh >> 4, h = bh & 15;
    const size_t base = (size_t)bh * LL * DD;
    const int kb0 = sp * 16;

    const int gq = qb * 128 + w * 16 + lr;
    bf16x8 qf[2];
    qf[0] = *reinterpret_cast<const bf16x8*>(Q + base + (size_t)gq * 64 + lg * 8);
    qf[1] = *reinterpret_cast<const bf16x8*>(Q + base + (size_t)gq * 64 + 32 + lg * 8);
    const __bf16* brow = biasB + (size_t)gq * 2048 + lg * 4;

    bf16x8 ones;
#pragma unroll
    for (int j = 0; j < 8; ++j) ones[j] = (__bf16)1.0f;

    // staging: wave w covers rows [w*8, w*8+8); lane: row w*8+(l>>3), 8 elems at (l&7)*8
    const int srow = w * 8 + (l >> 3);
    const int sce  = (l & 7) * 8;                  // element col
    const int smask = (srow & 7) << 4;             // (l>>3)<<4
    const __bf16* kgbase = K  + base + (size_t)srow * 64   + sce;
    const __bf16* vgbase = Vp + base + (size_t)srow * 2048 + sce;

    bf16x8 k0, v0;
    auto stage_regs = [&](int kb) {
        k0 = *reinterpret_cast<const bf16x8*>(kgbase + (size_t)kb * 64 * 64);
        v0 = *reinterpret_cast<const bf16x8*>(vgbase + kb * 64);
    };
    auto write_lds = [&](int buf) {
        *reinterpret_cast<bf16x8*>((char*)KVs[buf][0] + srow * 128 + ((sce * 2) ^ smask)) = k0;
        *reinterpret_cast<bf16x8*>((char*)KVs[buf][1] + srow * 128 + ((sce * 2) ^ smask)) = v0;
    };

    stage_regs(kb0);
    write_lds(0);

    f32x4 Oa[4] = {};
    f32x4 ls = {};
    int cur = 0;

    bf16x4 bcur[4];
#pragma unroll
    for (int t = 0; t < 4; ++t)
        bcur[t] = *reinterpret_cast<const bf16x4*>(brow + kb0 * 64 + t * 16);

    for (int kb = 0; kb < 16; ++kb) {
        __syncthreads();                    // buf[cur] published; buf[cur^1] free
        if (kb < 15) stage_regs(kb0 + kb + 1);

        bf16x4 bnext[4];
        if (kb < 15) {
#pragma unroll
            for (int t = 0; t < 4; ++t)
                bnext[t] = *reinterpret_cast<const bf16x4*>(brow + (kb0 + kb + 1) * 64 + t * 16);
        }

        const char* Kc = (const char*)KVs[cur][0];
        const char* Vc = (const char*)KVs[cur][1];

        // acc init = bias'(bf16); no cexp (cancels in O = sum(pv)/sum(p))
        f32x4 sa[4];
#pragma unroll
        for (int t = 0; t < 4; ++t)
#pragma unroll
            for (int r = 0; r < 4; ++r)
                sa[t][r] = (float)bcur[t][r];

        // S^T·log2e + bias' : lane q=lr, k = 16t+4lg+r
#pragma unroll
        for (int t = 0; t < 4; ++t) {
            const char* kr = Kc + (t * 16 + lr) * 128;
            bf16x8 kf0 = *reinterpret_cast<const bf16x8*>(kr + ((lg * 16) ^ rmask));
            bf16x8 kf1 = *reinterpret_cast<const bf16x8*>(kr + ((64 + lg * 16) ^ rmask));
            sa[t] = mfma_16x16x32(kf0, qf[0], sa[t]);
            sa[t] = mfma_16x16x32(kf1, qf[1], sa[t]);
        }

        // softmax: p = exp2(sa); pack lane-local values into A-operand slots
        float p[4][4];
#pragma unroll
        for (int t = 0; t < 4; ++t)
#pragma unroll
            for (int r = 0; r < 4; ++r)
                p[t][r] = exp2f(sa[t][r]);
        union Upa { unsigned u[4]; bf16x8 v; } pa0, pa1;
        pa0.u[0] = pk_bf16(p[0][0], p[0][1]); pa0.u[1] = pk_bf16(p[0][2], p[0][3]);
        pa0.u[2] = pk_bf16(p[1][0], p[1][1]); pa0.u[3] = pk_bf16(p[1][2], p[1][3]);
        pa1.u[0] = pk_bf16(p[2][0], p[2][1]); pa1.u[1] = pk_bf16(p[2][2], p[2][3]);
        pa1.u[2] = pk_bf16(p[3][0], p[3][1]); pa1.u[3] = pk_bf16(p[3][2], p[3][3]);

        // row-sum via MFMA (B = ones): ls rows = Oa rows
        ls = mfma_16x16x32(pa0.v, ones, ls);
        ls = mfma_16x16x32(pa1.v, ones, ls);

        // O += P·V : V pre-permuted globally -> contiguous b128 reads (same pattern as K)
#pragma unroll
        for (int t = 0; t < 4; ++t) {
            const char* vr = Vc + (t * 16 + lr) * 128;
            bf16x8 vf0 = *reinterpret_cast<const bf16x8*>(vr + ((lg * 16) ^ rmask));
            bf16x8 vf1 = *reinterpret_cast<const bf16x8*>(vr + ((64 + lg * 16) ^ rmask));
            Oa[t] = mfma_16x16x32(pa0.v, vf0, Oa[t]);
            Oa[t] = mfma_16x16x32(pa1.v, vf1, Oa[t]);
        }

        if (kb < 15) {
            write_lds(cur ^ 1);             // write-late; dep on loads forces vmcnt
#pragma unroll
            for (int t = 0; t < 4; ++t) bcur[t] = bnext[t];
        }
        cur ^= 1;
    }

    // partial outputs (no normalization; combine pass divides)
    float* Ofp = sp ? Of1 : Of0;
#pragma unroll
    for (int t = 0; t < 4; ++t)
#pragma unroll
        for (int r = 0; r < 4; ++r) {
            const int row = qb * 128 + w * 16 + lg * 4 + r;
            Ofp[((size_t)(b * 2048 + row)) * 1024 + h * 64 + t * 16 + lr] = Oa[t][r];
        }
    if (lr == 0) {
#pragma unroll
        for (int r = 0; r < 4; ++r) {
            const int row = qb * 128 + w * 16 + lg * 4 + r;
            lsF[((size_t)sp * 32 + bh) * 2048 + row] = ls[r];
        }
    }
}

// ---------------- combine: Oc = (Of0 + Of1) / (ls0 + ls1), bf16 ----------------
__global__ __launch_bounds__(256) void combine_kernel(
    const float* __restrict__ Of0, const float* __restrict__ Of1,
    const float* __restrict__ lsF, __bf16* __restrict__ Oc) {
    const int i = blockIdx.x * 256 + threadIdx.x;  // f32x4 group, 1M total
    const int e = i * 4;
    const int row = e >> 10;                       // b*2048 + l
    const int col = e & 1023;
    const int h = col >> 6;
    const int b = row >> 11, l = row & 2047;
    const size_t lsi = ((size_t)(b * 16 + h)) * 2048 + l;
    const float inv = 1.0f / (lsF[lsi] + lsF[(size_t)32 * 2048 + lsi]);
    float4 a = reinterpret_cast<const float4*>(Of0)[i];
    float4 c = reinterpret_cast<const float4*>(Of1)[i];
    bf16x4 o;
    o[0] = (__bf16)((a.x + c.x) * inv);
    o[1] = (__bf16)((a.y + c.y) * inv);
    o[2] = (__bf16)((a.z + c.z) * inv);
    o[3] = (__bf16)((a.w + c.w) * inv);
    reinterpret_cast<bf16x4*>(Oc)[i] = o;
}

// ---------------- launch ----------------
extern "C" void kernel_launch(void* const* d_in, const int* in_sizes, int n_in,
                              void* d_out, int out_size, void* d_ws, size_t ws_size,
                              hipStream_t stream) {
    const float* x         = (const float*)d_in[0];
    const float* attn_bias = (const float*)d_in[1];
    const float* W_qkv     = (const float*)d_in[2];
    const float* q_bias    = (const float*)d_in[3];
    const float* v_bias    = (const float*)d_in[4];
    const float* scale_mul = (const float*)d_in[5];
    const float* W_proj    = (const float*)d_in[6];
    const float* b_proj    = (const float*)d_in[7];
    float* out = (float*)d_out;

    char* ws = (char*)d_ws;
    size_t off = 0;
    auto alloc = [&](size_t bytes) {
        void* p = ws + off;
        off = (off + bytes + 255) & ~(size_t)255;
        return p;
    };
    // Vw and xb first: both dead by attn time -> Of partial 0 aliases [0, 16MB)
    __bf16* Vw      = (__bf16*)alloc((size_t)BB * HH * LL * DD * 2);   //  8 MB (off 0)
    __bf16* xb      = (__bf16*)alloc((size_t)4096 * 1024 * 2);         //  8 MB (off 8M)
    __bf16* wqkvb   = (__bf16*)alloc((size_t)3072 * 1024 * 2);         //  6 MB
    __bf16* wprojb  = (__bf16*)alloc((size_t)1024 * 1024 * 2);         //  2 MB
    __bf16* Qw      = (__bf16*)alloc((size_t)BB * HH * LL * DD * 2);   //  8 MB
    __bf16* Kw      = (__bf16*)alloc((size_t)BB * HH * LL * DD * 2);   //  8 MB
    __bf16* Oc      = (__bf16*)alloc((size_t)4096 * 1024 * 2);         //  8 MB
    __bf16* biasB   = (__bf16*)alloc((size_t)2048 * 2048 * 2);         //  8 MB
    __bf16* Vp      = (__bf16*)alloc((size_t)BB * HH * LL * DD * 2);   //  8 MB
    float*  Of1     = (float*)alloc((size_t)4096 * 1024 * 4);          // 16 MB (split 1)
    float*  lsF     = (float*)alloc((size_t)2 * 32 * 2048 * 4);        // 0.5 MB
    float*  Of0     = (float*)d_ws;   // split 0 aliases Vw+xb (both dead at attn time)

    cvt_bf16_kernel<<<4096, 256, 0, stream>>>(x, xb, 4096 * 1024 / 4);
    cvt_bf16_kernel<<<3072, 256, 0, stream>>>(W_qkv, wqkvb, 3072 * 1024 / 4);
    cvt_bf16_kernel<<<1024, 256, 0, stream>>>(W_proj, wprojb, 1024 * 1024 / 4);

    gemm_qkv_fused_kernel<<<dim3(32, 24), 256, 0, stream>>>(
        xb, wqkvb, q_bias, v_bias, scale_mul, Qw, Kw, Vw);

    bias_prep_kernel<<<2048, 256, 0, stream>>>(attn_bias, biasB);
    v_transpose_kernel<<<dim3(32, 32), 256, 0, stream>>>(Vw, Vp);

    attn_kernel<<<dim3(32, 16, 2), 512, 0, stream>>>(Qw, Kw, Vp, biasB, Of0, Of1, lsF);

    combine_kernel<<<4096, 256, 0, stream>>>(Of0, Of1, lsF, Oc);

    gemm_proj_kernel<<<dim3(32, 8), 256, 0, stream>>>(
        Oc, wprojb, out, b_proj, 4096, 1024, 1024);
}